// Round 4
// baseline (625.831 us; speedup 1.0000x reference)
//
#include <hip/hip_runtime.h>
#include <math.h>

#define NUM_LEVELS 16
#define LEVEL_DIM 2
#define LOG2_T 21
#define TABLE_SIZE (1u << LOG2_T)
#define HASH_MASK (TABLE_SIZE - 1u)
#define N_POINTS 262144
#define TILE_PTS 1024
#define NTILES (N_POINTS / TILE_PTS)      // 256 tiles per level
#define GRID_P1 1536
#define WS_CTR_BYTES 512

#define PX 73856093u
#define PY 19349663u
#define PZ 83492791u

struct Args { float r[NUM_LEVELS]; int l2nc[NUM_LEVELS]; };

__device__ __forceinline__ int get_xcd() {
    int v;
    asm volatile("s_getreg_b32 %0, hwreg(HW_REG_XCC_ID)" : "=s"(v));
    return v & 7;
}

__device__ __forceinline__ void process_tile(
    const float* __restrict__ x,
    const float* __restrict__ tables,
    float2* __restrict__ wsbuf,
    const Args& args, int lv, int t)
{
    const float r = args.r[lv];
    const int l2nc = args.l2nc[lv];
    const int shift = LOG2_T - l2nc;
    const int nc = 1 << l2nc;
    const float* __restrict__ tab =
        tables + (size_t)lv * ((size_t)TABLE_SIZE * LEVEL_DIM);

    const int base = t * TILE_PTS + threadIdx.x;   // 4 pts, stride 256

    float wx[4], wy[4], wz[4];
    uint32_t hx[4], hy[4], hz[4];
    float a0[4], a1[4];

    #pragma unroll
    for (int p = 0; p < 4; ++p) {
        const int n = base + p * 256;
        const float px = x[n * 3 + 0];
        const float py = x[n * 3 + 1];
        const float pz = x[n * 3 + 2];
        const float nx = fminf(fmaxf((px + 2.0f) * 0.25f, 0.0f), 1.0f);
        const float ny = fminf(fmaxf((py + 2.0f) * 0.25f, 0.0f), 1.0f);
        const float nz = fminf(fmaxf((pz + 2.0f) * 0.25f, 0.0f), 1.0f);
        const float sx = nx * r, sy = ny * r, sz = nz * r;
        const float fx = floorf(sx), fy = floorf(sy), fz = floorf(sz);
        wx[p] = sx - fx; wy[p] = sy - fy; wz[p] = sz - fz;
        hx[p] = (uint32_t)(int)fx * PX;
        hy[p] = (uint32_t)(int)fy * PY;
        hz[p] = (uint32_t)(int)fz * PZ;
        a0[p] = 0.0f; a1[p] = 0.0f;
    }

    for (int c = 0; c < nc; ++c) {
        #pragma unroll
        for (int p = 0; p < 4; ++p) {
            const uint32_t X0 = hx[p], Y0 = hy[p], Z0 = hz[p];
            const uint32_t X1 = X0 + PX, Y1 = Y0 + PY, Z1 = Z0 + PZ;
            const float qx = wx[p], qy = wy[p], qz = wz[p];
            const float ax = 1.0f - qx, ay = 1.0f - qy, az = 1.0f - qz;
            #pragma unroll
            for (int cc = 0; cc < 8; ++cc) {
                const uint32_t h = ((cc & 4) ? X1 : X0) ^ ((cc & 2) ? Y1 : Y0)
                                 ^ ((cc & 1) ? Z1 : Z0);
                const uint32_t idx = h & HASH_MASK;
                if ((int)(idx >> shift) == c) {
                    const float2 e =
                        *reinterpret_cast<const float2*>(tab + (size_t)idx * LEVEL_DIM);
                    const float w = (((cc & 4) ? qx : ax) * ((cc & 2) ? qy : ay))
                                  * ((cc & 1) ? qz : az);
                    a0[p] = fmaf(w, e.x, a0[p]);
                    a1[p] = fmaf(w, e.y, a1[p]);
                }
            }
        }
    }

    #pragma unroll
    for (int p = 0; p < 4; ++p) {
        wsbuf[(size_t)lv * N_POINTS + base + p * 256] = make_float2(a0[p], a1[p]);
    }
}

// ---- phase 1: XCD-pinned levels, hash-chunked gathers, work-stealing -------
__global__ __launch_bounds__(256) void hash_embed_phase1_xcd(
    const float* __restrict__ x,
    const float* __restrict__ tables,
    int* __restrict__ cnt,            // [16] zeroed before launch
    float2* __restrict__ wsbuf,       // [NUM_LEVELS][N_POINTS]
    Args args)
{
    const int xcd = get_xcd();
    const int lvA = xcd;
    const int lvB = 15 - xcd;

    __shared__ int s_t;

    for (int phase = 0; phase < 18; ++phase) {
        int lv;
        if (phase == 0) lv = lvA;
        else if (phase == 1) lv = lvB;
        else lv = phase - 2;            // steal sweep guarantees completion
        for (;;) {
            __syncthreads();
            if (threadIdx.x == 0) s_t = atomicAdd(&cnt[lv], 1);
            __syncthreads();
            const int t = s_t;
            if (t >= NTILES) break;
            process_tile(x, tables, wsbuf, args, lv, t);
        }
    }
}

// ---- phase 2: transpose ws[l][n] -> out[n][l] ------------------------------
__global__ __launch_bounds__(256) void hash_embed_phase2(
    const float2* __restrict__ ws,
    float2* __restrict__ out)
{
    __shared__ float2 tile[64][NUM_LEVELS + 1];
    const int n0 = blockIdx.x * 64;
    const int t = threadIdx.x;
    #pragma unroll
    for (int k = 0; k < 4; ++k) {
        const int e = k * 256 + t;
        const int l = e >> 6;
        const int j = e & 63;
        tile[j][l] = ws[(size_t)l * N_POINTS + n0 + j];
    }
    __syncthreads();
    #pragma unroll
    for (int k = 0; k < 4; ++k) {
        const int e = k * 256 + t;
        const int nl = e >> 4;
        const int l = e & 15;
        out[(size_t)(n0 + nl) * NUM_LEVELS + l] = tile[nl][l];
    }
}

// ---- fallback (R1-proven): interleaved levels, direct out ------------------
__global__ __launch_bounds__(256) void hash_embed_direct(
    const float* __restrict__ x,
    const float* __restrict__ tables,
    float* __restrict__ out,
    Args args)
{
    const int t = blockIdx.x * blockDim.x + threadIdx.x;
    const int n = t >> 4;
    const int l = t & 15;
    if (n >= N_POINTS) return;

    const float px = x[n * 3 + 0];
    const float py = x[n * 3 + 1];
    const float pz = x[n * 3 + 2];
    const float nx = fminf(fmaxf((px + 2.0f) * 0.25f, 0.0f), 1.0f);
    const float ny = fminf(fmaxf((py + 2.0f) * 0.25f, 0.0f), 1.0f);
    const float nz = fminf(fmaxf((pz + 2.0f) * 0.25f, 0.0f), 1.0f);

    const float r = args.r[l];
    const float sx = nx * r, sy = ny * r, sz = nz * r;
    const float fx = floorf(sx), fy = floorf(sy), fz = floorf(sz);
    const float wxv = sx - fx, wyv = sy - fy, wzv = sz - fz;

    const uint32_t hx0 = (uint32_t)(int)fx * PX;
    const uint32_t hy0 = (uint32_t)(int)fy * PY;
    const uint32_t hz0 = (uint32_t)(int)fz * PZ;
    const uint32_t hx1 = hx0 + PX, hy1 = hy0 + PY, hz1 = hz0 + PZ;

    const float ax = 1.0f - wxv, ay = 1.0f - wyv, az = 1.0f - wzv;
    const float* __restrict__ tab = tables + (size_t)l * ((size_t)TABLE_SIZE * LEVEL_DIM);

    float f0 = 0.0f, f1 = 0.0f;
    #pragma unroll
    for (int c = 0; c < 8; ++c) {
        const uint32_t hh = ((c & 4) ? hx1 : hx0) ^ ((c & 2) ? hy1 : hy0)
                          ^ ((c & 1) ? hz1 : hz0);
        const uint32_t idx = hh & HASH_MASK;
        const float2 emb = *reinterpret_cast<const float2*>(tab + (size_t)idx * LEVEL_DIM);
        const float w = (((c & 4) ? wxv : ax) * ((c & 2) ? wyv : ay)) * ((c & 1) ? wzv : az);
        f0 = fmaf(w, emb.x, f0);
        f1 = fmaf(w, emb.y, f1);
    }
    float2* o = reinterpret_cast<float2*>(out + (size_t)n * (NUM_LEVELS * LEVEL_DIM) + l * LEVEL_DIM);
    *o = make_float2(f0, f1);
}

extern "C" void kernel_launch(void* const* d_in, const int* in_sizes, int n_in,
                              void* d_out, int out_size, void* d_ws, size_t ws_size,
                              hipStream_t stream) {
    const float* x      = (const float*)d_in[0];
    const float* tables = (const float*)d_in[1];
    float* out          = (float*)d_out;

    Args args;
    const double b = exp((log(2048.0) - log(16.0)) / 15.0);
    for (int i = 0; i < NUM_LEVELS; ++i) {
        const double ri = floor(16.0 * pow(b, (double)i));
        args.r[i] = (float)ri;
        // accessed-footprint estimate -> chunk count (pow2, <=8)
        double entries = (ri + 1.0) * (ri + 1.0) * (ri + 1.0);
        if (entries > (double)TABLE_SIZE) entries = (double)TABLE_SIZE;
        const double lines = 262144.0 * (1.0 - exp(-entries / 262144.0));
        const double fp_mb = lines * 64.0 / 1.0e6;
        int l2 = 0;
        if (fp_mb > 3.0) {
            int ncc = (int)ceil(fp_mb / 2.5);
            while ((1 << l2) < ncc) ++l2;
            if (l2 > 3) l2 = 3;          // cap NC=8
        }
        args.l2nc[i] = l2;
    }

    const size_t ws_needed = WS_CTR_BYTES + (size_t)NUM_LEVELS * N_POINTS * sizeof(float2);
    if (ws_size >= ws_needed) {
        int* cnt = (int*)d_ws;
        float2* wsbuf = (float2*)((char*)d_ws + WS_CTR_BYTES);
        hipMemsetAsync(d_ws, 0, WS_CTR_BYTES, stream);
        hipLaunchKernelGGL(hash_embed_phase1_xcd, dim3(GRID_P1), dim3(256),
                           0, stream, x, tables, cnt, wsbuf, args);
        hipLaunchKernelGGL(hash_embed_phase2, dim3(N_POINTS / 64), dim3(256),
                           0, stream, wsbuf, (float2*)out);
    } else {
        const int total = N_POINTS * NUM_LEVELS;
        hipLaunchKernelGGL(hash_embed_direct, dim3((total + 255) / 256), dim3(256),
                           0, stream, x, tables, out, args);
    }
}

// Round 5
// 444.893 us; speedup vs baseline: 1.4067x; 1.4067x over previous
//
#include <hip/hip_runtime.h>
#include <math.h>

#define NUM_LEVELS 16
#define LEVEL_DIM 2
#define LOG2_T 21
#define TABLE_SIZE (1u << LOG2_T)
#define HASH_MASK (TABLE_SIZE - 1u)
#define N_POINTS 262144
#define GRID_P1 2048          // 256 slices x 8 xcd-slots
#define PTS_PER_BLOCK 1024    // 4 pts/thread x 256 threads

#define PX 73856093u
#define PY 19349663u
#define PZ 83492791u

struct Args { float r[NUM_LEVELS]; int l2nc[NUM_LEVELS]; };

__device__ __forceinline__ void process_level(
    const float* __restrict__ x,
    const float* __restrict__ tables,
    float2* __restrict__ wsbuf,
    const Args& args, int lv, int slice)
{
    const float r = args.r[lv];
    const int l2nc = args.l2nc[lv];
    const int shift = LOG2_T - l2nc;   // nc==1 -> shift=21 -> idx>>21==0==c always
    const int nc = 1 << l2nc;
    const float* __restrict__ tab =
        tables + (size_t)lv * ((size_t)TABLE_SIZE * LEVEL_DIM);

    const int base = slice * PTS_PER_BLOCK + threadIdx.x;   // 4 pts, stride 256

    float wx[4], wy[4], wz[4];
    uint32_t hx[4], hy[4], hz[4];
    float a0[4], a1[4];

    #pragma unroll
    for (int p = 0; p < 4; ++p) {
        const int n = base + p * 256;
        const float px = x[n * 3 + 0];
        const float py = x[n * 3 + 1];
        const float pz = x[n * 3 + 2];
        const float nx = fminf(fmaxf((px + 2.0f) * 0.25f, 0.0f), 1.0f);
        const float ny = fminf(fmaxf((py + 2.0f) * 0.25f, 0.0f), 1.0f);
        const float nz = fminf(fmaxf((pz + 2.0f) * 0.25f, 0.0f), 1.0f);
        const float sx = nx * r, sy = ny * r, sz = nz * r;
        const float fx = floorf(sx), fy = floorf(sy), fz = floorf(sz);
        wx[p] = sx - fx; wy[p] = sy - fy; wz[p] = sz - fz;
        hx[p] = (uint32_t)(int)fx * PX;
        hy[p] = (uint32_t)(int)fy * PY;
        hz[p] = (uint32_t)(int)fz * PZ;
        a0[p] = 0.0f; a1[p] = 0.0f;
    }

    for (int c = 0; c < nc; ++c) {
        #pragma unroll
        for (int p = 0; p < 4; ++p) {
            const uint32_t X0 = hx[p], Y0 = hy[p], Z0 = hz[p];
            const uint32_t X1 = X0 + PX, Y1 = Y0 + PY, Z1 = Z0 + PZ;
            const float qx = wx[p], qy = wy[p], qz = wz[p];
            const float ax = 1.0f - qx, ay = 1.0f - qy, az = 1.0f - qz;
            #pragma unroll
            for (int cc = 0; cc < 8; ++cc) {
                const uint32_t h = ((cc & 4) ? X1 : X0) ^ ((cc & 2) ? Y1 : Y0)
                                 ^ ((cc & 1) ? Z1 : Z0);
                const uint32_t idx = h & HASH_MASK;
                if ((int)(idx >> shift) == c) {
                    const float2 e =
                        *reinterpret_cast<const float2*>(tab + (size_t)idx * LEVEL_DIM);
                    const float w = (((cc & 4) ? qx : ax) * ((cc & 2) ? qy : ay))
                                  * ((cc & 1) ? qz : az);
                    a0[p] = fmaf(w, e.x, a0[p]);
                    a1[p] = fmaf(w, e.y, a1[p]);
                }
            }
        }
    }

    #pragma unroll
    for (int p = 0; p < 4; ++p) {
        wsbuf[(size_t)lv * N_POINTS + base + p * 256] = make_float2(a0[p], a1[p]);
    }
}

// ---- phase 1: static XCD-pinned levels, L2-sized hash chunks ---------------
__global__ __launch_bounds__(256) void hash_embed_phase1_static(
    const float* __restrict__ x,
    const float* __restrict__ tables,
    float2* __restrict__ wsbuf,       // [NUM_LEVELS][N_POINTS]
    Args args)
{
    const int bid = blockIdx.x;
    const int xcd = bid & 7;          // round-robin dispatch heuristic (perf-only)
    const int slice = bid >> 3;       // 0..255
    process_level(x, tables, wsbuf, args, xcd, slice);        // level = xcd
    process_level(x, tables, wsbuf, args, 15 - xcd, slice);   // then mirror level
}

// ---- phase 2: transpose ws[l][n] -> out[n][l] ------------------------------
__global__ __launch_bounds__(256) void hash_embed_phase2(
    const float2* __restrict__ ws,
    float2* __restrict__ out)
{
    __shared__ float2 tile[64][NUM_LEVELS + 1];
    const int n0 = blockIdx.x * 64;
    const int t = threadIdx.x;
    #pragma unroll
    for (int k = 0; k < 4; ++k) {
        const int e = k * 256 + t;
        const int l = e >> 6;
        const int j = e & 63;
        tile[j][l] = ws[(size_t)l * N_POINTS + n0 + j];
    }
    __syncthreads();
    #pragma unroll
    for (int k = 0; k < 4; ++k) {
        const int e = k * 256 + t;
        const int nl = e >> 4;
        const int l = e & 15;
        out[(size_t)(n0 + nl) * NUM_LEVELS + l] = tile[nl][l];
    }
}

// ---- fallback (R1-proven): interleaved levels, direct out ------------------
__global__ __launch_bounds__(256) void hash_embed_direct(
    const float* __restrict__ x,
    const float* __restrict__ tables,
    float* __restrict__ out,
    Args args)
{
    const int t = blockIdx.x * blockDim.x + threadIdx.x;
    const int n = t >> 4;
    const int l = t & 15;
    if (n >= N_POINTS) return;

    const float px = x[n * 3 + 0];
    const float py = x[n * 3 + 1];
    const float pz = x[n * 3 + 2];
    const float nx = fminf(fmaxf((px + 2.0f) * 0.25f, 0.0f), 1.0f);
    const float ny = fminf(fmaxf((py + 2.0f) * 0.25f, 0.0f), 1.0f);
    const float nz = fminf(fmaxf((pz + 2.0f) * 0.25f, 0.0f), 1.0f);

    const float r = args.r[l];
    const float sx = nx * r, sy = ny * r, sz = nz * r;
    const float fx = floorf(sx), fy = floorf(sy), fz = floorf(sz);
    const float wxv = sx - fx, wyv = sy - fy, wzv = sz - fz;

    const uint32_t hx0 = (uint32_t)(int)fx * PX;
    const uint32_t hy0 = (uint32_t)(int)fy * PY;
    const uint32_t hz0 = (uint32_t)(int)fz * PZ;
    const uint32_t hx1 = hx0 + PX, hy1 = hy0 + PY, hz1 = hz0 + PZ;

    const float ax = 1.0f - wxv, ay = 1.0f - wyv, az = 1.0f - wzv;
    const float* __restrict__ tab = tables + (size_t)l * ((size_t)TABLE_SIZE * LEVEL_DIM);

    float f0 = 0.0f, f1 = 0.0f;
    #pragma unroll
    for (int c = 0; c < 8; ++c) {
        const uint32_t hh = ((c & 4) ? hx1 : hx0) ^ ((c & 2) ? hy1 : hy0)
                          ^ ((c & 1) ? hz1 : hz0);
        const uint32_t idx = hh & HASH_MASK;
        const float2 emb = *reinterpret_cast<const float2*>(tab + (size_t)idx * LEVEL_DIM);
        const float w = (((c & 4) ? wxv : ax) * ((c & 2) ? wyv : ay)) * ((c & 1) ? wzv : az);
        f0 = fmaf(w, emb.x, f0);
        f1 = fmaf(w, emb.y, f1);
    }
    float2* o = reinterpret_cast<float2*>(out + (size_t)n * (NUM_LEVELS * LEVEL_DIM) + l * LEVEL_DIM);
    *o = make_float2(f0, f1);
}

extern "C" void kernel_launch(void* const* d_in, const int* in_sizes, int n_in,
                              void* d_out, int out_size, void* d_ws, size_t ws_size,
                              hipStream_t stream) {
    const float* x      = (const float*)d_in[0];
    const float* tables = (const float*)d_in[1];
    float* out          = (float*)d_out;

    Args args;
    const double b = exp((log(2048.0) - log(16.0)) / 15.0);
    for (int i = 0; i < NUM_LEVELS; ++i) {
        const double ri = floor(16.0 * pow(b, (double)i));
        args.r[i] = (float)ri;
        // accessed-footprint model: distinct corners E spread hash-randomly
        // over 2^21 slots (8 entries per 64B line)
        double E = (ri + 1.0) * (ri + 1.0) * (ri + 1.0);
        if (E > 1.8e6) E = 1.8e6;
        const double lines = 262144.0 * (1.0 - exp(-8.0 * E / 2097152.0));
        const double bytes = lines * 64.0;
        int nc = (int)ceil(bytes / 2.5e6);
        if (nc < 1) nc = 1;
        int l2 = 0;
        while ((1 << l2) < nc) ++l2;
        if (l2 > 3) l2 = 3;            // cap NC=8 (2 MB chunks, 2 fit in L2)
        args.l2nc[i] = l2;
    }

    const size_t ws_needed = (size_t)NUM_LEVELS * N_POINTS * sizeof(float2); // 32 MB
    if (ws_size >= ws_needed) {
        float2* wsbuf = (float2*)d_ws;
        hipLaunchKernelGGL(hash_embed_phase1_static, dim3(GRID_P1), dim3(256),
                           0, stream, x, tables, wsbuf, args);
        hipLaunchKernelGGL(hash_embed_phase2, dim3(N_POINTS / 64), dim3(256),
                           0, stream, wsbuf, (float2*)out);
    } else {
        const int total = N_POINTS * NUM_LEVELS;
        hipLaunchKernelGGL(hash_embed_direct, dim3((total + 255) / 256), dim3(256),
                           0, stream, x, tables, out, args);
    }
}